// Round 3
// baseline (1360.250 us; speedup 1.0000x reference)
//
#include <hip/hip_runtime.h>
#include <stdint.h>

#define NLV 8
#define KCB 1024
#define DM  512
#define NTOK (8*4096)
#define BETA 0.00390625f   // 2^-8 bias keeps lo-planes f16-normal; folds into c2'

typedef _Float16 f16;
typedef f16  f16x4 __attribute__((ext_vector_type(4)));
typedef f16  f16x8 __attribute__((ext_vector_type(8)));
typedef float f32x4 __attribute__((ext_vector_type(4)));

typedef __attribute__((address_space(1))) const unsigned int* as1p;
typedef __attribute__((address_space(3))) unsigned int*       as3p;
__device__ __forceinline__ void gll16(const void* g, void* l) {
    __builtin_amdgcn_global_load_lds((as1p)g, (as3p)l, 16, 0, 0);
}

// counted vmcnt: lets the 10 newest (next-kstep) loads stay in flight while
// guaranteeing everything older (current kstep's A-gll + B-reg loads) landed.
#define VMCNT(n) asm volatile("s_waitcnt vmcnt(" #n ")" ::: "memory")

// ---------------- c2' precompute: sum(c^2) + 2*beta*sum(f16(c)) ----------------
__global__ void c2_kernel(const float* __restrict__ cbs, float* __restrict__ c2) {
    int row  = blockIdx.x;
    int lane = threadIdx.x;
    const float4* p4 = (const float4*)(cbs + (size_t)row * DM);
    float4 a = p4[lane];
    float4 b = p4[lane + 64];
    float s = a.x*a.x + a.y*a.y + a.z*a.z + a.w*a.w
            + b.x*b.x + b.y*b.y + b.z*b.z + b.w*b.w;
    float t = (float)(f16)a.x + (float)(f16)a.y + (float)(f16)a.z + (float)(f16)a.w
            + (float)(f16)b.x + (float)(f16)b.y + (float)(f16)b.z + (float)(f16)b.w;
    #pragma unroll
    for (int off = 32; off > 0; off >>= 1) {
        s += __shfl_down(s, off, 64);
        t += __shfl_down(t, off, 64);
    }
    if (lane == 0) c2[row] = s + 2.0f * BETA * t;
}

// ---------------- hi/lo split with bias ----------------
__global__ void split_kernel(const float* __restrict__ src,
                             f16* __restrict__ hi, f16* __restrict__ lo) {
    size_t i = (size_t)blockIdx.x * 256 + threadIdx.x;   // float4 index
    float4 v = ((const float4*)src)[i];
    f16x4 h, l;
    h.x = (f16)v.x; l.x = (f16)((v.x - (float)h.x) + BETA);
    h.y = (f16)v.y; l.y = (f16)((v.y - (float)h.y) + BETA);
    h.z = (f16)v.z; l.z = (f16)((v.z - (float)h.z) + BETA);
    h.w = (f16)v.w; l.w = (f16)((v.w - (float)h.w) + BETA);
    ((f16x4*)hi)[i] = h;
    ((f16x4*)lo)[i] = l;
}

// ---------------- main MFMA level kernel ----------------
// 256 threads = 4 waves, each wave = one 64-cb N-strip; M=64 tokens/block.
// Data-path restructure (round 3): B planes have ZERO intra-block reuse
// (disjoint per-wave cb strips), so B skips LDS entirely: direct global->reg
// loads, double-buffered E/O register sets, prefetched one kstep ahead.
// A (shared by all 4 waves) keeps the validated LDS path: granule-swizzled
// global_load_lds double buffer, 0 bank conflicts. Per kstep per wave:
// 2 gll + 8 global_load_dwordx4 + 8 ds_read_b128 + 48 MFMA, one raw
// s_barrier + vmcnt(10). B addressing is SGPR-base + loop-invariant VGPR
// offset (0 VALU/load); A is per-thread base ptr + scalar kstep offset.
#define MBT  64
#define NCH  256
#define KS   32
#define NTHR 256
#define ABUF 8192    // Ahi 4K | Alo 4K

__global__ __launch_bounds__(NTHR, 2)
void rvq_mfma(const float* __restrict__ xin, float* __restrict__ qout,
              const float* __restrict__ cbs,
              const f16* __restrict__ Bhi, const f16* __restrict__ Blo,
              f16* __restrict__ Ahi, f16* __restrict__ Alo,
              const float* __restrict__ c2g, float* __restrict__ idxout,
              int lvl, int is_last)
{
    __shared__ char smem[2 * ABUF];      // 16 KB
    const int tid  = threadIdx.x;
    const int lane = tid & 63;
    const int wn   = tid >> 6;           // 0..3  N strip (64 codebooks)
    const int tx   = lane & 15;
    const int q    = lane >> 4;
    const size_t tok0 = (size_t)blockIdx.x * MBT;

    const f16*   Bh_l = Bhi + (size_t)lvl * KCB * DM;
    const f16*   Bl_l = Blo + (size_t)lvl * KCB * DM;
    const float* c2l  = c2g + lvl * KCB;
    const float* cbl  = cbs + (size_t)lvl * KCB * DM;

    // A staging: thread tid covers row srow, granule-position tid&3; fetched
    // granule g = pos ^ ((row>>1)&3). LDS slot = tid*16 within each plane.
    const int srow = tid >> 2;                       // 0..63
    const int sg   = (tid & 3) ^ ((srow >> 1) & 3);
    const int rsw  = q ^ ((tx >> 1) & 3);            // read-side granule pos

    // per-thread A base pointers (hoists all 64-bit address math out of loop)
    const f16* pA0 = Ahi + (tok0 + srow) * (size_t)DM + sg * 8;
    const f16* pL0 = Alo + (tok0 + srow) * (size_t)DM + sg * 8;

    auto stageA = [&](char* buf, int gk2) {
        const int kOff = (gk2 & 15) * KS;            // scalar
        char* wb = buf + wn * 1024;                  // wave-uniform base
        gll16(pA0 + kOff, wb);
        gll16(pL0 + kOff, wb + 4096);
    };

    // B: loop-invariant per-lane element offsets (SADDR + voffset form)
    int loffB[4];
    #pragma unroll
    for (int j = 0; j < 4; ++j)
        loffB[j] = (wn * 64 + j * 16 + tx) * DM + q * 8;

    auto loadB = [&](int gk2, f16x8 (&bh)[4], f16x8 (&bl)[4]) {
        const int sOff = ((gk2 >> 4) * NCH) * DM + (gk2 & 15) * KS;  // scalar
        const f16* pbh = Bh_l + sOff;
        const f16* pbl = Bl_l + sOff;
        #pragma unroll
        for (int j = 0; j < 4; ++j) {
            bh[j] = *(const f16x8*)(pbh + loffB[j]);
            bl[j] = *(const f16x8*)(pbl + loffB[j]);
        }
    };

    // A fragment byte offsets within planes (undo granule swizzle)
    int aoff[4];
    #pragma unroll
    for (int i = 0; i < 4; ++i) aoff[i] = (i * 16 + tx) * 64 + rsw * 16;

    float bestv[16];
    int   besti[16];
    #pragma unroll
    for (int t = 0; t < 16; ++t) { bestv[t] = 3.4e38f; besti[t] = 0; }

    // B register double buffer (all indexing static -> stays in VGPRs)
    f16x8 bhE[4], blE[4], bhO[4], blO[4];

    // prologue: B(0) into E set, A(0) into buf0 (10 loads in flight)
    loadB(0, bhE, blE);
    stageA(smem, 0);

    for (int ch = 0; ch < KCB / NCH; ++ch) {
        f32x4 acc[4][4];
        #pragma unroll
        for (int i = 0; i < 4; ++i)
            #pragma unroll
            for (int j = 0; j < 4; ++j) acc[i][j] = (f32x4)0.0f;

        auto kbody = [&](int gk, f16x8 (&bhc)[4], f16x8 (&blc)[4],
                         f16x8 (&bhn)[4], f16x8 (&bln)[4]) {
            const int nx = (gk + 1) & 63;            // wrap keeps vmcnt uniform
            char* bb = smem + (gk & 1) * ABUF;
            char* bn = smem + ((gk & 1) ^ 1) * ABUF;

            loadB(nx, bhn, bln);                     // 8 loads (k+1)
            stageA(bn, nx);                          // 2 gll   (k+1)
            __builtin_amdgcn_sched_barrier(0);
            VMCNT(10);                               // A(k)+B(k) complete
            __builtin_amdgcn_s_barrier();            // raw: no drain
            __builtin_amdgcn_sched_barrier(0);

            f16x8 ah[4], al[4];
            #pragma unroll
            for (int i = 0; i < 4; ++i) ah[i] = *(const f16x8*)(bb + aoff[i]);
            #pragma unroll
            for (int i = 0; i < 4; ++i) al[i] = *(const f16x8*)(bb + 4096 + aoff[i]);

            __builtin_amdgcn_s_setprio(1);
            #pragma unroll
            for (int j = 0; j < 4; ++j)
                #pragma unroll
                for (int i = 0; i < 4; ++i)
                    acc[i][j] = __builtin_amdgcn_mfma_f32_16x16x32_f16(ah[i], bhc[j], acc[i][j], 0, 0, 0);
            #pragma unroll
            for (int j = 0; j < 4; ++j)
                #pragma unroll
                for (int i = 0; i < 4; ++i)
                    acc[i][j] = __builtin_amdgcn_mfma_f32_16x16x32_f16(ah[i], blc[j], acc[i][j], 0, 0, 0);
            #pragma unroll
            for (int j = 0; j < 4; ++j)
                #pragma unroll
                for (int i = 0; i < 4; ++i)
                    acc[i][j] = __builtin_amdgcn_mfma_f32_16x16x32_f16(al[i], bhc[j], acc[i][j], 0, 0, 0);
            __builtin_amdgcn_s_setprio(0);
        };

        for (int kp = 0; kp < 8; ++kp) {             // 16 ksteps as E/O pairs
            const int gk = ch * 16 + kp * 2;
            kbody(gk,     bhE, blE, bhO, blO);
            kbody(gk + 1, bhO, blO, bhE, blE);
        }

        // chunk argmin epilogue (C/D: col=lane&15, row=(lane>>4)*4+reg)
        const int cb0 = ch * NCH;
        #pragma unroll
        for (int j = 0; j < 4; ++j) {
            int n = cb0 + wn * 64 + j * 16 + tx;
            float c2v = c2l[n];
            #pragma unroll
            for (int i = 0; i < 4; ++i)
                #pragma unroll
                for (int r = 0; r < 4; ++r) {
                    float s = fmaf(-2.f, acc[i][j][r], c2v);
                    int t = i * 4 + r;
                    if (s < bestv[t]) { bestv[t] = s; besti[t] = n; }
                }
        }
    }

    // cross-lane argmin over tx (16 lanes; same q -> same token rows)
    #pragma unroll
    for (int t = 0; t < 16; ++t) {
        float v = bestv[t]; int bi = besti[t];
        #pragma unroll
        for (int off = 1; off < 16; off <<= 1) {
            float ov = __shfl_xor(v, off, 64);
            int   oi = __shfl_xor(bi, off, 64);
            if (ov < v || (ov == v && oi < bi)) { v = ov; bi = oi; }
        }
        bestv[t] = v; besti[t] = bi;
    }

    // cross-wave reduce over the 4 wn strips; overlay on buf0.
    // __syncthreads drains vmcnt(0): tail wrap-stage writes into buf0
    // complete before the overlay is used.
    float* redV = (float*)smem;            // [4 wn][64 m]  1 KB
    int*   redI = (int*)(smem + 1024);     // 1 KB
    int*   kbst = (int*)(smem + 2048);     // 64 ints
    __syncthreads();
    if (tx == 0) {
        #pragma unroll
        for (int i = 0; i < 4; ++i)
            #pragma unroll
            for (int r = 0; r < 4; ++r) {
                int m = i * 16 + q * 4 + r;
                redV[wn * 64 + m] = bestv[i * 4 + r];
                redI[wn * 64 + m] = besti[i * 4 + r];
            }
    }
    __syncthreads();
    if (tid < MBT) {
        float bv = redV[tid]; int bi = redI[tid];
        #pragma unroll
        for (int w = 1; w < 4; ++w) {
            float v  = redV[w * 64 + tid];
            int   ii = redI[w * 64 + tid];
            if (v < bv || (v == bv && ii < bi)) { bv = v; bi = ii; }
        }
        kbst[tid] = bi;
        idxout[(tok0 + tid) * NLV + lvl] = (float)bi;
    }
    __syncthreads();

    // residual update on biased hi/lo planes: r = hi + (lo - beta) - c
    #pragma unroll 4
    for (int it = 0; it < 16; ++it) {
        int e  = it * NTHR + tid;          // 64 tok x 64 granules of 8
        int t  = e >> 6, d8 = e & 63;
        size_t go = (tok0 + t) * (size_t)DM + d8 * 8;
        f16x8 h8 = *(const f16x8*)&Ahi[go];
        f16x8 l8 = *(const f16x8*)&Alo[go];
        const float* cp = &cbl[(size_t)kbst[t] * DM + d8 * 8];
        float4 c0 = *(const float4*)cp;
        float4 c1 = *(const float4*)(cp + 4);
        float r[8];
        r[0] = (float)h8[0] + ((float)l8[0] - BETA) - c0.x;
        r[1] = (float)h8[1] + ((float)l8[1] - BETA) - c0.y;
        r[2] = (float)h8[2] + ((float)l8[2] - BETA) - c0.z;
        r[3] = (float)h8[3] + ((float)l8[3] - BETA) - c0.w;
        r[4] = (float)h8[4] + ((float)l8[4] - BETA) - c1.x;
        r[5] = (float)h8[5] + ((float)l8[5] - BETA) - c1.y;
        r[6] = (float)h8[6] + ((float)l8[6] - BETA) - c1.z;
        r[7] = (float)h8[7] + ((float)l8[7] - BETA) - c1.w;
        if (is_last) {
            float4 x0 = *(const float4*)&xin[go];
            float4 x1 = *(const float4*)&xin[go + 4];
            float4 q0 = make_float4(x0.x - r[0], x0.y - r[1], x0.z - r[2], x0.w - r[3]);
            float4 q1 = make_float4(x1.x - r[4], x1.y - r[5], x1.z - r[6], x1.w - r[7]);
            *(float4*)&qout[go]     = q0;
            *(float4*)&qout[go + 4] = q1;
        } else {
            f16x8 h, l;
            #pragma unroll
            for (int k = 0; k < 8; ++k) {
                h[k] = (f16)r[k];
                l[k] = (f16)((r[k] - (float)h[k]) + BETA);
            }
            *(f16x8*)&Ahi[go] = h;
            *(f16x8*)&Alo[go] = l;
        }
    }
}

// =================== launch ===================
extern "C" void kernel_launch(void* const* d_in, const int* in_sizes, int n_in,
                              void* d_out, int out_size, void* d_ws, size_t ws_size,
                              hipStream_t stream) {
    const float* x   = (const float*)d_in[0];   // [8,4096,512]
    const float* cbs = (const float*)d_in[1];   // [8,1024,512]
    float* qout   = (float*)d_out;                       // [8,4096,512]
    float* idxout = qout + (size_t)NTOK * DM;            // [8,4096,8] as float

    const size_t B_ELE = (size_t)NLV * KCB * DM;   // 4,194,304
    const size_t A_ELE = (size_t)NTOK * DM;        // 16,777,216

    f16* Bhi = (f16*)d_ws;
    f16* Blo = Bhi + B_ELE;
    f16* Ahi = Blo + B_ELE;
    f16* Alo = Ahi + A_ELE;
    float* c2 = (float*)(Alo + A_ELE);

    split_kernel<<<(int)(B_ELE / 4 / 256), 256, 0, stream>>>(cbs, Bhi, Blo);
    split_kernel<<<(int)(A_ELE / 4 / 256), 256, 0, stream>>>(x, Ahi, Alo);
    c2_kernel<<<NLV * KCB, 64, 0, stream>>>(cbs, c2);

    const int nblocks = NTOK / MBT;  // 512 -> 2 blocks/CU
    for (int l = 0; l < NLV; ++l) {
        rvq_mfma<<<nblocks, NTHR, 0, stream>>>(x, qout, cbs,
                                               Bhi, Blo, Ahi, Alo, c2, idxout,
                                               l, (l == NLV - 1) ? 1 : 0);
    }
}

// Round 5
// 1270.228 us; speedup vs baseline: 1.0709x; 1.0709x over previous
//
#include <hip/hip_runtime.h>
#include <stdint.h>

#define NLV 8
#define KCB 1024
#define DM  512
#define NTOK (8*4096)
#define BETA 0.00390625f   // 2^-8 bias keeps lo-planes f16-normal; folds into c2'

typedef _Float16 f16;
typedef f16  f16x4 __attribute__((ext_vector_type(4)));
typedef f16  f16x8 __attribute__((ext_vector_type(8)));
typedef float f32x4 __attribute__((ext_vector_type(4)));

typedef __attribute__((address_space(1))) const unsigned int* as1p;
typedef __attribute__((address_space(3))) unsigned int*       as3p;
__device__ __forceinline__ void gll16(const void* g, void* l) {
    __builtin_amdgcn_global_load_lds((as1p)g, (as3p)l, 16, 0, 0);
}

// ---------------- c2' precompute: sum(c^2) + 2*beta*sum(f16(c)) ----------------
__global__ void c2_kernel(const float* __restrict__ cbs, float* __restrict__ c2) {
    int row  = blockIdx.x;
    int lane = threadIdx.x;
    const float4* p4 = (const float4*)(cbs + (size_t)row * DM);
    float4 a = p4[lane];
    float4 b = p4[lane + 64];
    float s = a.x*a.x + a.y*a.y + a.z*a.z + a.w*a.w
            + b.x*b.x + b.y*b.y + b.z*b.z + b.w*b.w;
    float t = (float)(f16)a.x + (float)(f16)a.y + (float)(f16)a.z + (float)(f16)a.w
            + (float)(f16)b.x + (float)(f16)b.y + (float)(f16)b.z + (float)(f16)b.w;
    #pragma unroll
    for (int off = 32; off > 0; off >>= 1) {
        s += __shfl_down(s, off, 64);
        t += __shfl_down(t, off, 64);
    }
    if (lane == 0) c2[row] = s + 2.0f * BETA * t;
}

// ---------------- hi/lo split with bias ----------------
__global__ void split_kernel(const float* __restrict__ src,
                             f16* __restrict__ hi, f16* __restrict__ lo) {
    size_t i = (size_t)blockIdx.x * 256 + threadIdx.x;   // float4 index
    float4 v = ((const float4*)src)[i];
    f16x4 h, l;
    h.x = (f16)v.x; l.x = (f16)((v.x - (float)h.x) + BETA);
    h.y = (f16)v.y; l.y = (f16)((v.y - (float)h.y) + BETA);
    h.z = (f16)v.z; l.z = (f16)((v.z - (float)h.z) + BETA);
    h.w = (f16)v.w; l.w = (f16)((v.w - (float)h.w) + BETA);
    ((f16x4*)hi)[i] = h;
    ((f16x4*)lo)[i] = l;
}

// ---------------- main MFMA level kernel ----------------
// Round 5: R4's 8-wave occupancy geometry + R0's provably race-free sync.
// 512 thr = 8 waves (grid 2M x 4N), each wave 32 tok x 64 cb; LDS 80 KB ->
// 2 blocks/CU -> 16 waves/CU (4/SIMD), VGPR<=128 via launch_bounds(512,4).
// R4's correctness bug: stage-before-barrier wrote the buffer sibling waves
// were still ds_reading (safe at 2 waves/SIMD by latency, racy at 4/SIMD
// with prio-1 MFMA clusters starving laggard waves). Fix = R0 ordering:
// __syncthreads() (drains vmcnt+lgkmcnt) BEFORE stage -> no wave writes a
// buffer until all waves completed their reads of it. R2 proved the
// vmcnt(0) drain costs ~nothing vs counted vmcnt.
// Staging: 5 gll/wave (waves 0-3: Ahi chunk + 4 Bh chunks; waves 4-7: Alo
// + Bl), granule swizzle sg=(lane&3)^((lane>>3)&3), 0 bank conflicts.
#define MBT  64
#define NCH  256
#define KS   32
#define NTHR 512
#define BUFB 40960   // Ahi 4K | Alo 4K | Bh 16K | Bl 16K

__global__ __launch_bounds__(NTHR, 4)
void rvq_mfma(const float* __restrict__ xin, float* __restrict__ qout,
              const float* __restrict__ cbs,
              const f16* __restrict__ Bhi, const f16* __restrict__ Blo,
              f16* __restrict__ Ahi, f16* __restrict__ Alo,
              const float* __restrict__ c2g, float* __restrict__ idxout,
              int lvl, int is_last)
{
    __shared__ char smem[2 * BUFB];      // 81920 B -> exactly 2 blocks/CU
    const int tid  = threadIdx.x;
    const int lane = tid & 63;
    const int w    = tid >> 6;           // 0..7
    const int wn   = w & 3;              // N strip (64 codebooks)
    const int wm   = w >> 2;             // M half (32 tokens)
    const int tx   = lane & 15;
    const int q    = lane >> 4;
    const size_t tok0 = (size_t)blockIdx.x * MBT;

    const f16*   Bh_l = Bhi + (size_t)lvl * KCB * DM;
    const f16*   Bl_l = Blo + (size_t)lvl * KCB * DM;
    const float* c2l  = c2g + lvl * KCB;
    const float* cbl  = cbs + (size_t)lvl * KCB * DM;

    // ---- staging assignment (5 gll per wave) ----
    // lane l stages row_local = l>>2, granule-pos l&3 of a 16-row 1KB chunk;
    // fetched data-granule sg = (l&3) ^ ((row>>1)&3) = (l&3) ^ ((l>>3)&3).
    const int rloc = lane >> 2;                      // 0..15
    const int sg   = (lane & 3) ^ ((lane >> 3) & 3);
    const int rsw  = q ^ ((tx >> 1) & 3);            // read-side granule pos

    // A: wave w stages chunk (w&3) of plane (w<4 ? Ahi : Alo)
    const int arow = (w & 3) * 16 + rloc;            // token row staged
    const f16* pA  = (w < 4 ? Ahi : Alo) + (tok0 + arow) * (size_t)DM + sg * 8;
    const int aLds = (w < 4 ? 0 : 4096) + (w & 3) * 1024;   // wave-uniform

    // B: wave w stages chunks c = 4w..4w+3 (c<16 -> Bh, else Bl);
    // LDS dest unifies to 8192 + c*1024 for both planes.
    const f16* pB = (w < 4 ? Bh_l : Bl_l);
    int bElo[4];                                     // per-thread element offs
    #pragma unroll
    for (int i = 0; i < 4; ++i)
        bElo[i] = (((w & 3) * 4 + i) * 16 + rloc) * DM + sg * 8;

    auto stage = [&](char* buf, int gk2) {
        const int ko  = (gk2 & 15) * KS;             // scalar
        const int cb0 = (gk2 >> 4) * NCH;            // scalar
        gll16(pA + ko, buf + aLds);
        const size_t bo = (size_t)cb0 * DM + ko;
        #pragma unroll
        for (int i = 0; i < 4; ++i)
            gll16(pB + bo + bElo[i], buf + 8192 + (w * 4 + i) * 1024);
    };

    // ---- read-side fragment byte offsets ----
    int aoff[2], boff[4];
    #pragma unroll
    for (int i = 0; i < 2; ++i) aoff[i] = (wm * 32 + i * 16 + tx) * 64 + rsw * 16;
    #pragma unroll
    for (int j = 0; j < 4; ++j) boff[j] = (wn * 64 + j * 16 + tx) * 64 + rsw * 16;

    float bestv[8];
    int   besti[8];
    #pragma unroll
    for (int t = 0; t < 8; ++t) { bestv[t] = 3.4e38f; besti[t] = 0; }

    stage(smem, 0);   // prologue: buf0 for gk=0 (drained by first syncthreads)

    for (int ch = 0; ch < KCB / NCH; ++ch) {
        f32x4 acc[2][4];
        #pragma unroll
        for (int i = 0; i < 2; ++i)
            #pragma unroll
            for (int j = 0; j < 4; ++j) acc[i][j] = (f32x4)0.0f;

        for (int kk = 0; kk < 16; ++kk) {
            const int gk = ch * 16 + kk;             // 0..63
            char* bb = smem + (gk & 1) * BUFB;
            char* bn = smem + ((gk & 1) ^ 1) * BUFB;

            __syncthreads();                         // drains gk-1 prefetch AND
                                                     // all waves' reads of bn
            if (gk + 1 < 64)
                stage(bn, gk + 1);                   // 5 loads (k+1)

            f16x8 ah[2], al[2], bh[4], bl[4];
            #pragma unroll
            for (int i = 0; i < 2; ++i) {
                ah[i] = *(const f16x8*)(bb + aoff[i]);
                al[i] = *(const f16x8*)(bb + 4096 + aoff[i]);
            }
            #pragma unroll
            for (int j = 0; j < 4; ++j) {
                bh[j] = *(const f16x8*)(bb + 8192 + boff[j]);
                bl[j] = *(const f16x8*)(bb + 24576 + boff[j]);
            }

            __builtin_amdgcn_s_setprio(1);
            #pragma unroll
            for (int j = 0; j < 4; ++j)
                #pragma unroll
                for (int i = 0; i < 2; ++i)
                    acc[i][j] = __builtin_amdgcn_mfma_f32_16x16x32_f16(ah[i], bh[j], acc[i][j], 0, 0, 0);
            #pragma unroll
            for (int j = 0; j < 4; ++j)
                #pragma unroll
                for (int i = 0; i < 2; ++i)
                    acc[i][j] = __builtin_amdgcn_mfma_f32_16x16x32_f16(ah[i], bl[j], acc[i][j], 0, 0, 0);
            #pragma unroll
            for (int j = 0; j < 4; ++j)
                #pragma unroll
                for (int i = 0; i < 2; ++i)
                    acc[i][j] = __builtin_amdgcn_mfma_f32_16x16x32_f16(al[i], bh[j], acc[i][j], 0, 0, 0);
            __builtin_amdgcn_s_setprio(0);
        }

        // chunk argmin epilogue (C/D: col=lane&15 -> cb, row=(lane>>4)*4+reg -> token)
        const int cb0 = ch * NCH;
        #pragma unroll
        for (int j = 0; j < 4; ++j) {
            int n = cb0 + wn * 64 + j * 16 + tx;
            float c2v = c2l[n];
            #pragma unroll
            for (int i = 0; i < 2; ++i)
                #pragma unroll
                for (int r = 0; r < 4; ++r) {
                    float s = fmaf(-2.f, acc[i][j][r], c2v);
                    int t = i * 4 + r;
                    if (s < bestv[t]) { bestv[t] = s; besti[t] = n; }
                }
        }
    }

    // cross-lane argmin over tx (16 lanes; same q -> same token rows)
    #pragma unroll
    for (int t = 0; t < 8; ++t) {
        float v = bestv[t]; int bi = besti[t];
        #pragma unroll
        for (int off = 1; off < 16; off <<= 1) {
            float ov = __shfl_xor(v, off, 64);
            int   oi = __shfl_xor(bi, off, 64);
            if (ov < v || (ov == v && oi < bi)) { v = ov; bi = oi; }
        }
        bestv[t] = v; besti[t] = bi;
    }

    // cross-wave reduce over the 4 wn strips; overlay on buf0 (reads retired,
    // __syncthreads drains any outstanding ops first).
    float* redV = (float*)smem;            // [4 wn][64 m]  1 KB
    int*   redI = (int*)(smem + 1024);     // 1 KB
    int*   kbst = (int*)(smem + 2048);     // 64 ints
    __syncthreads();
    if (tx == 0) {
        #pragma unroll
        for (int i = 0; i < 2; ++i)
            #pragma unroll
            for (int r = 0; r < 4; ++r) {
                int m = wm * 32 + i * 16 + q * 4 + r;
                redV[wn * 64 + m] = bestv[i * 4 + r];
                redI[wn * 64 + m] = besti[i * 4 + r];
            }
    }
    __syncthreads();
    if (tid < MBT) {
        float bv = redV[tid]; int bi = redI[tid];
        #pragma unroll
        for (int ww = 1; ww < 4; ++ww) {
            float v  = redV[ww * 64 + tid];
            int   ii = redI[ww * 64 + tid];
            if (v < bv || (v == bv && ii < bi)) { bv = v; bi = ii; }
        }
        kbst[tid] = bi;
        idxout[(tok0 + tid) * NLV + lvl] = (float)bi;
    }
    __syncthreads();

    // residual update on biased hi/lo planes: r = hi + (lo - beta) - c
    #pragma unroll 4
    for (int it = 0; it < 8; ++it) {
        int e  = it * NTHR + tid;          // 64 tok x 64 granules of 8
        int t  = e >> 6, d8 = e & 63;
        size_t go = (tok0 + t) * (size_t)DM + d8 * 8;
        f16x8 h8 = *(const f16x8*)&Ahi[go];
        f16x8 l8 = *(const f16x8*)&Alo[go];
        const float* cp = &cbl[(size_t)kbst[t] * DM + d8 * 8];
        float4 c0 = *(const float4*)cp;
        float4 c1 = *(const float4*)(cp + 4);
        float r[8];
        r[0] = (float)h8[0] + ((float)l8[0] - BETA) - c0.x;
        r[1] = (float)h8[1] + ((float)l8[1] - BETA) - c0.y;
        r[2] = (float)h8[2] + ((float)l8[2] - BETA) - c0.z;
        r[3] = (float)h8[3] + ((float)l8[3] - BETA) - c0.w;
        r[4] = (float)h8[4] + ((float)l8[4] - BETA) - c1.x;
        r[5] = (float)h8[5] + ((float)l8[5] - BETA) - c1.y;
        r[6] = (float)h8[6] + ((float)l8[6] - BETA) - c1.z;
        r[7] = (float)h8[7] + ((float)l8[7] - BETA) - c1.w;
        if (is_last) {
            float4 x0 = *(const float4*)&xin[go];
            float4 x1 = *(const float4*)&xin[go + 4];
            float4 q0 = make_float4(x0.x - r[0], x0.y - r[1], x0.z - r[2], x0.w - r[3]);
            float4 q1 = make_float4(x1.x - r[4], x1.y - r[5], x1.z - r[6], x1.w - r[7]);
            *(float4*)&qout[go]     = q0;
            *(float4*)&qout[go + 4] = q1;
        } else {
            f16x8 h, l;
            #pragma unroll
            for (int k = 0; k < 8; ++k) {
                h[k] = (f16)r[k];
                l[k] = (f16)((r[k] - (float)h[k]) + BETA);
            }
            *(f16x8*)&Ahi[go] = h;
            *(f16x8*)&Alo[go] = l;
        }
    }
}

// =================== launch ===================
extern "C" void kernel_launch(void* const* d_in, const int* in_sizes, int n_in,
                              void* d_out, int out_size, void* d_ws, size_t ws_size,
                              hipStream_t stream) {
    const float* x   = (const float*)d_in[0];   // [8,4096,512]
    const float* cbs = (const float*)d_in[1];   // [8,1024,512]
    float* qout   = (float*)d_out;                       // [8,4096,512]
    float* idxout = qout + (size_t)NTOK * DM;            // [8,4096,8] as float

    const size_t B_ELE = (size_t)NLV * KCB * DM;   // 4,194,304
    const size_t A_ELE = (size_t)NTOK * DM;        // 16,777,216

    f16* Bhi = (f16*)d_ws;
    f16* Blo = Bhi + B_ELE;
    f16* Ahi = Blo + B_ELE;
    f16* Alo = Ahi + A_ELE;
    float* c2 = (float*)(Alo + A_ELE);

    split_kernel<<<(int)(B_ELE / 4 / 256), 256, 0, stream>>>(cbs, Bhi, Blo);
    split_kernel<<<(int)(A_ELE / 4 / 256), 256, 0, stream>>>(x, Ahi, Alo);
    c2_kernel<<<NLV * KCB, 64, 0, stream>>>(cbs, c2);

    const int nblocks = NTOK / MBT;  // 512 -> 2 blocks/CU
    for (int l = 0; l < NLV; ++l) {
        rvq_mfma<<<nblocks, NTHR, 0, stream>>>(x, qout, cbs,
                                               Bhi, Blo, Ahi, Alo, c2, idxout,
                                               l, (l == NLV - 1) ? 1 : 0);
    }
}

// Round 6
// 1205.480 us; speedup vs baseline: 1.1284x; 1.0537x over previous
//
#include <hip/hip_runtime.h>
#include <stdint.h>

#define NLV 8
#define KCB 1024
#define DM  512
#define NTOK (8*4096)
#define BETA 0.00390625f   // 2^-8 bias keeps lo-planes f16-normal; folds into c2'

typedef _Float16 f16;
typedef f16  f16x4 __attribute__((ext_vector_type(4)));
typedef f16  f16x8 __attribute__((ext_vector_type(8)));
typedef float f32x4 __attribute__((ext_vector_type(4)));

typedef __attribute__((address_space(1))) const unsigned int* as1p;
typedef __attribute__((address_space(3))) unsigned int*       as3p;
__device__ __forceinline__ void gll16(const void* g, void* l) {
    __builtin_amdgcn_global_load_lds((as1p)g, (as3p)l, 16, 0, 0);
}

// ---------------- c2' precompute: sum(c^2) + 2*beta*sum(f16(c)) ----------------
__global__ void c2_kernel(const float* __restrict__ cbs, float* __restrict__ c2) {
    int row  = blockIdx.x;
    int lane = threadIdx.x;
    const float4* p4 = (const float4*)(cbs + (size_t)row * DM);
    float4 a = p4[lane];
    float4 b = p4[lane + 64];
    float s = a.x*a.x + a.y*a.y + a.z*a.z + a.w*a.w
            + b.x*b.x + b.y*b.y + b.z*b.z + b.w*b.w;
    float t = (float)(f16)a.x + (float)(f16)a.y + (float)(f16)a.z + (float)(f16)a.w
            + (float)(f16)b.x + (float)(f16)b.y + (float)(f16)b.z + (float)(f16)b.w;
    #pragma unroll
    for (int off = 32; off > 0; off >>= 1) {
        s += __shfl_down(s, off, 64);
        t += __shfl_down(t, off, 64);
    }
    if (lane == 0) c2[row] = s + 2.0f * BETA * t;
}

// ---------------- hi/lo split with bias ----------------
__global__ void split_kernel(const float* __restrict__ src,
                             f16* __restrict__ hi, f16* __restrict__ lo) {
    size_t i = (size_t)blockIdx.x * 256 + threadIdx.x;   // float4 index
    float4 v = ((const float4*)src)[i];
    f16x4 h, l;
    h.x = (f16)v.x; l.x = (f16)((v.x - (float)h.x) + BETA);
    h.y = (f16)v.y; l.y = (f16)((v.y - (float)h.y) + BETA);
    h.z = (f16)v.z; l.z = (f16)((v.z - (float)h.z) + BETA);
    h.w = (f16)v.w; l.w = (f16)((v.w - (float)h.w) + BETA);
    ((f16x4*)hi)[i] = h;
    ((f16x4*)lo)[i] = l;
}

// ---------------- main MFMA level kernel ----------------
// Round 6 = Round 5 despilled. R5 evidence: VGPR_Count=64 (allocator chased
// 8 waves/EU), +82MB FETCH / +44MB WRITE vs R0 = scratch spill signature.
// Fixes: (1) amdgpu_waves_per_eu(4,4) pins occupancy at 4 waves/EU so the
// allocator uses the full 128-VGPR budget instead of spilling to reach 64;
// (2) B fragments processed in two j-halves (12-MFMA clusters) to cut peak
// register liveness (~105 regs, no-spill margin). Per-acc accumulation
// order unchanged (hh,hl,lh per acc) -> bitwise-identical results to R5.
// Geometry unchanged from R5 (passed): 512 thr = 8 waves (2M x 4N), each
// wave 32 tok x 64 cb; LDS 80KB -> 2 blocks/CU -> 16 waves/CU; R0-style
// race-free sync (__syncthreads BEFORE stage).
#define MBT  64
#define NCH  256
#define KS   32
#define NTHR 512
#define BUFB 40960   // Ahi 4K | Alo 4K | Bh 16K | Bl 16K

__global__ __launch_bounds__(NTHR, 4) __attribute__((amdgpu_waves_per_eu(4, 4)))
void rvq_mfma(const float* __restrict__ xin, float* __restrict__ qout,
              const float* __restrict__ cbs,
              const f16* __restrict__ Bhi, const f16* __restrict__ Blo,
              f16* __restrict__ Ahi, f16* __restrict__ Alo,
              const float* __restrict__ c2g, float* __restrict__ idxout,
              int lvl, int is_last)
{
    __shared__ char smem[2 * BUFB];      // 81920 B -> exactly 2 blocks/CU
    const int tid  = threadIdx.x;
    const int lane = tid & 63;
    const int w    = tid >> 6;           // 0..7
    const int wn   = w & 3;              // N strip (64 codebooks)
    const int wm   = w >> 2;             // M half (32 tokens)
    const int tx   = lane & 15;
    const int q    = lane >> 4;
    const size_t tok0 = (size_t)blockIdx.x * MBT;

    const f16*   Bh_l = Bhi + (size_t)lvl * KCB * DM;
    const f16*   Bl_l = Blo + (size_t)lvl * KCB * DM;
    const float* c2l  = c2g + lvl * KCB;
    const float* cbl  = cbs + (size_t)lvl * KCB * DM;

    // ---- staging assignment (5 gll per wave) ----
    // lane l stages row_local = l>>2, granule-pos l&3 of a 16-row 1KB chunk;
    // fetched data-granule sg = (l&3) ^ ((row>>1)&3) = (l&3) ^ ((l>>3)&3).
    const int rloc = lane >> 2;                      // 0..15
    const int sg   = (lane & 3) ^ ((lane >> 3) & 3);
    const int rsw  = q ^ ((tx >> 1) & 3);            // read-side granule pos

    // A: wave w stages chunk (w&3) of plane (w<4 ? Ahi : Alo)
    const int arow = (w & 3) * 16 + rloc;            // token row staged
    const f16* pA  = (w < 4 ? Ahi : Alo) + (tok0 + arow) * (size_t)DM + sg * 8;
    const int aLds = (w < 4 ? 0 : 4096) + (w & 3) * 1024;   // wave-uniform

    // B: wave w stages chunks c = 4w..4w+3 (c<16 -> Bh, else Bl);
    // LDS dest unifies to 8192 + c*1024 for both planes.
    const f16* pB = (w < 4 ? Bh_l : Bl_l);
    int bElo[4];                                     // per-thread element offs
    #pragma unroll
    for (int i = 0; i < 4; ++i)
        bElo[i] = (((w & 3) * 4 + i) * 16 + rloc) * DM + sg * 8;

    auto stage = [&](char* buf, int gk2) {
        const int ko  = (gk2 & 15) * KS;             // scalar
        const int cb0 = (gk2 >> 4) * NCH;            // scalar
        gll16(pA + ko, buf + aLds);
        const size_t bo = (size_t)cb0 * DM + ko;
        #pragma unroll
        for (int i = 0; i < 4; ++i)
            gll16(pB + bo + bElo[i], buf + 8192 + (w * 4 + i) * 1024);
    };

    // ---- read-side fragment byte offsets ----
    int aoff[2], boff[4];
    #pragma unroll
    for (int i = 0; i < 2; ++i) aoff[i] = (wm * 32 + i * 16 + tx) * 64 + rsw * 16;
    #pragma unroll
    for (int j = 0; j < 4; ++j) boff[j] = (wn * 64 + j * 16 + tx) * 64 + rsw * 16;

    float bestv[8];
    int   besti[8];
    #pragma unroll
    for (int t = 0; t < 8; ++t) { bestv[t] = 3.4e38f; besti[t] = 0; }

    stage(smem, 0);   // prologue: buf0 for gk=0 (drained by first syncthreads)

    for (int ch = 0; ch < KCB / NCH; ++ch) {
        f32x4 acc[2][4];
        #pragma unroll
        for (int i = 0; i < 2; ++i)
            #pragma unroll
            for (int j = 0; j < 4; ++j) acc[i][j] = (f32x4)0.0f;

        for (int kk = 0; kk < 16; ++kk) {
            const int gk = ch * 16 + kk;             // 0..63
            char* bb = smem + (gk & 1) * BUFB;
            char* bn = smem + ((gk & 1) ^ 1) * BUFB;

            __syncthreads();                         // drains gk-1 prefetch AND
                                                     // all waves' reads of bn
            if (gk + 1 < 64)
                stage(bn, gk + 1);                   // 5 loads (k+1)

            f16x8 ah[2], al[2];
            #pragma unroll
            for (int i = 0; i < 2; ++i) {
                ah[i] = *(const f16x8*)(bb + aoff[i]);
                al[i] = *(const f16x8*)(bb + 4096 + aoff[i]);
            }

            // two j-halves: peak B-frag liveness 16 regs instead of 32.
            // Per acc[i][j] the pass order stays hh,hl,lh (bitwise same).
            #pragma unroll
            for (int jh = 0; jh < 2; ++jh) {
                f16x8 bh[2], bl[2];
                #pragma unroll
                for (int j2 = 0; j2 < 2; ++j2) {
                    bh[j2] = *(const f16x8*)(bb +  8192 + boff[jh * 2 + j2]);
                    bl[j2] = *(const f16x8*)(bb + 24576 + boff[jh * 2 + j2]);
                }
                __builtin_amdgcn_s_setprio(1);
                #pragma unroll
                for (int j2 = 0; j2 < 2; ++j2)
                    #pragma unroll
                    for (int i = 0; i < 2; ++i)
                        acc[i][jh * 2 + j2] = __builtin_amdgcn_mfma_f32_16x16x32_f16(
                            ah[i], bh[j2], acc[i][jh * 2 + j2], 0, 0, 0);
                #pragma unroll
                for (int j2 = 0; j2 < 2; ++j2)
                    #pragma unroll
                    for (int i = 0; i < 2; ++i)
                        acc[i][jh * 2 + j2] = __builtin_amdgcn_mfma_f32_16x16x32_f16(
                            ah[i], bl[j2], acc[i][jh * 2 + j2], 0, 0, 0);
                #pragma unroll
                for (int j2 = 0; j2 < 2; ++j2)
                    #pragma unroll
                    for (int i = 0; i < 2; ++i)
                        acc[i][jh * 2 + j2] = __builtin_amdgcn_mfma_f32_16x16x32_f16(
                            al[i], bh[j2], acc[i][jh * 2 + j2], 0, 0, 0);
                __builtin_amdgcn_s_setprio(0);
            }
        }

        // chunk argmin epilogue (C/D: col=lane&15 -> cb, row=(lane>>4)*4+reg -> token)
        const int cb0 = ch * NCH;
        #pragma unroll
        for (int j = 0; j < 4; ++j) {
            int n = cb0 + wn * 64 + j * 16 + tx;
            float c2v = c2l[n];
            #pragma unroll
            for (int i = 0; i < 2; ++i)
                #pragma unroll
                for (int r = 0; r < 4; ++r) {
                    float s = fmaf(-2.f, acc[i][j][r], c2v);
                    int t = i * 4 + r;
                    if (s < bestv[t]) { bestv[t] = s; besti[t] = n; }
                }
        }
    }

    // cross-lane argmin over tx (16 lanes; same q -> same token rows)
    #pragma unroll
    for (int t = 0; t < 8; ++t) {
        float v = bestv[t]; int bi = besti[t];
        #pragma unroll
        for (int off = 1; off < 16; off <<= 1) {
            float ov = __shfl_xor(v, off, 64);
            int   oi = __shfl_xor(bi, off, 64);
            if (ov < v || (ov == v && oi < bi)) { v = ov; bi = oi; }
        }
        bestv[t] = v; besti[t] = bi;
    }

    // cross-wave reduce over the 4 wn strips; overlay on buf0 (reads retired,
    // __syncthreads drains any outstanding ops first).
    float* redV = (float*)smem;            // [4 wn][64 m]  1 KB
    int*   redI = (int*)(smem + 1024);     // 1 KB
    int*   kbst = (int*)(smem + 2048);     // 64 ints
    __syncthreads();
    if (tx == 0) {
        #pragma unroll
        for (int i = 0; i < 2; ++i)
            #pragma unroll
            for (int r = 0; r < 4; ++r) {
                int m = wm * 32 + i * 16 + q * 4 + r;
                redV[wn * 64 + m] = bestv[i * 4 + r];
                redI[wn * 64 + m] = besti[i * 4 + r];
            }
    }
    __syncthreads();
    if (tid < MBT) {
        float bv = redV[tid]; int bi = redI[tid];
        #pragma unroll
        for (int ww = 1; ww < 4; ++ww) {
            float v  = redV[ww * 64 + tid];
            int   ii = redI[ww * 64 + tid];
            if (v < bv || (v == bv && ii < bi)) { bv = v; bi = ii; }
        }
        kbst[tid] = bi;
        idxout[(tok0 + tid) * NLV + lvl] = (float)bi;
    }
    __syncthreads();

    // residual update on biased hi/lo planes: r = hi + (lo - beta) - c
    #pragma unroll 4
    for (int it = 0; it < 8; ++it) {
        int e  = it * NTHR + tid;          // 64 tok x 64 granules of 8
        int t  = e >> 6, d8 = e & 63;
        size_t go = (tok0 + t) * (size_t)DM + d8 * 8;
        f16x8 h8 = *(const f16x8*)&Ahi[go];
        f16x8 l8 = *(const f16x8*)&Alo[go];
        const float* cp = &cbl[(size_t)kbst[t] * DM + d8 * 8];
        float4 c0 = *(const float4*)cp;
        float4 c1 = *(const float4*)(cp + 4);
        float r[8];
        r[0] = (float)h8[0] + ((float)l8[0] - BETA) - c0.x;
        r[1] = (float)h8[1] + ((float)l8[1] - BETA) - c0.y;
        r[2] = (float)h8[2] + ((float)l8[2] - BETA) - c0.z;
        r[3] = (float)h8[3] + ((float)l8[3] - BETA) - c0.w;
        r[4] = (float)h8[4] + ((float)l8[4] - BETA) - c1.x;
        r[5] = (float)h8[5] + ((float)l8[5] - BETA) - c1.y;
        r[6] = (float)h8[6] + ((float)l8[6] - BETA) - c1.z;
        r[7] = (float)h8[7] + ((float)l8[7] - BETA) - c1.w;
        if (is_last) {
            float4 x0 = *(const float4*)&xin[go];
            float4 x1 = *(const float4*)&xin[go + 4];
            float4 q0 = make_float4(x0.x - r[0], x0.y - r[1], x0.z - r[2], x0.w - r[3]);
            float4 q1 = make_float4(x1.x - r[4], x1.y - r[5], x1.z - r[6], x1.w - r[7]);
            *(float4*)&qout[go]     = q0;
            *(float4*)&qout[go + 4] = q1;
        } else {
            f16x8 h, l;
            #pragma unroll
            for (int k = 0; k < 8; ++k) {
                h[k] = (f16)r[k];
                l[k] = (f16)((r[k] - (float)h[k]) + BETA);
            }
            *(f16x8*)&Ahi[go] = h;
            *(f16x8*)&Alo[go] = l;
        }
    }
}

// =================== launch ===================
extern "C" void kernel_launch(void* const* d_in, const int* in_sizes, int n_in,
                              void* d_out, int out_size, void* d_ws, size_t ws_size,
                              hipStream_t stream) {
    const float* x   = (const float*)d_in[0];   // [8,4096,512]
    const float* cbs = (const float*)d_in[1];   // [8,1024,512]
    float* qout   = (float*)d_out;                       // [8,4096,512]
    float* idxout = qout + (size_t)NTOK * DM;            // [8,4096,8] as float

    const size_t B_ELE = (size_t)NLV * KCB * DM;   // 4,194,304
    const size_t A_ELE = (size_t)NTOK * DM;        // 16,777,216

    f16* Bhi = (f16*)d_ws;
    f16* Blo = Bhi + B_ELE;
    f16* Ahi = Blo + B_ELE;
    f16* Alo = Ahi + A_ELE;
    float* c2 = (float*)(Alo + A_ELE);

    split_kernel<<<(int)(B_ELE / 4 / 256), 256, 0, stream>>>(cbs, Bhi, Blo);
    split_kernel<<<(int)(A_ELE / 4 / 256), 256, 0, stream>>>(x, Ahi, Alo);
    c2_kernel<<<NLV * KCB, 64, 0, stream>>>(cbs, c2);

    const int nblocks = NTOK / MBT;  // 512 -> 2 blocks/CU
    for (int l = 0; l < NLV; ++l) {
        rvq_mfma<<<nblocks, NTHR, 0, stream>>>(x, qout, cbs,
                                               Bhi, Blo, Ahi, Alo, c2, idxout,
                                               l, (l == NLV - 1) ? 1 : 0);
    }
}

// Round 7
// 1136.174 us; speedup vs baseline: 1.1972x; 1.0610x over previous
//
#include <hip/hip_runtime.h>
#include <stdint.h>

#define NLV 8
#define KCB 1024
#define DM  512
#define NTOK (8*4096)
#define BETA 0.00390625f   // 2^-8 bias keeps lo-planes f16-normal; folds into c2'

typedef _Float16 f16;
typedef f16  f16x4 __attribute__((ext_vector_type(4)));
typedef f16  f16x8 __attribute__((ext_vector_type(8)));
typedef float f32x4 __attribute__((ext_vector_type(4)));

typedef __attribute__((address_space(1))) const unsigned int* as1p;
typedef __attribute__((address_space(3))) unsigned int*       as3p;
__device__ __forceinline__ void gll16(const void* g, void* l) {
    __builtin_amdgcn_global_load_lds((as1p)g, (as3p)l, 16, 0, 0);
}

// ---------------- c2' precompute: sum(c^2) + 2*beta*sum(f16(c)) ----------------
__global__ void c2_kernel(const float* __restrict__ cbs, float* __restrict__ c2) {
    int row  = blockIdx.x;
    int lane = threadIdx.x;
    const float4* p4 = (const float4*)(cbs + (size_t)row * DM);
    float4 a = p4[lane];
    float4 b = p4[lane + 64];
    float s = a.x*a.x + a.y*a.y + a.z*a.z + a.w*a.w
            + b.x*b.x + b.y*b.y + b.z*b.z + b.w*b.w;
    float t = (float)(f16)a.x + (float)(f16)a.y + (float)(f16)a.z + (float)(f16)a.w
            + (float)(f16)b.x + (float)(f16)b.y + (float)(f16)b.z + (float)(f16)b.w;
    #pragma unroll
    for (int off = 32; off > 0; off >>= 1) {
        s += __shfl_down(s, off, 64);
        t += __shfl_down(t, off, 64);
    }
    if (lane == 0) c2[row] = s + 2.0f * BETA * t;
}

// ---------------- hi/lo split with bias ----------------
__global__ void split_kernel(const float* __restrict__ src,
                             f16* __restrict__ hi, f16* __restrict__ lo) {
    size_t i = (size_t)blockIdx.x * 256 + threadIdx.x;   // float4 index
    float4 v = ((const float4*)src)[i];
    f16x4 h, l;
    h.x = (f16)v.x; l.x = (f16)((v.x - (float)h.x) + BETA);
    h.y = (f16)v.y; l.y = (f16)((v.y - (float)h.y) + BETA);
    h.z = (f16)v.z; l.z = (f16)((v.z - (float)h.z) + BETA);
    h.w = (f16)v.w; l.w = (f16)((v.w - (float)h.w) + BETA);
    ((f16x4*)hi)[i] = h;
    ((f16x4*)lo)[i] = l;
}

// ---------------- main MFMA level kernel ----------------
// Round 7: M-TILE restructure. R0/R2/R5/R6 established the kstep period
// (~5300 cyc) is invariant to barrier schedule and wave count -> limiter is
// staged VOLUME per MFMA (serial pipe sum: MFMA 1862 + DMA ~1300 + VALU).
// Fix: M=128 tokens/block (256 blocks), 512 thr = 8 waves (2M x 4N), each
// wave 64 tok x 64 cb (acc[4][4], the R0 per-wave shape). B staged bytes
// per MFMA HALVE: per-CU per-kstep staging drops 80 KB -> 48 KB for the
// same matrix work. LDS 2x48 KB = 96 KB -> 1 block/CU, 2 waves/SIMD (same
// as R0 - proven not the limiter), VGPR budget 256 via launch_bounds(512,2)
// -> the 64-reg allocator squeeze of R5/R6 is impossible, no spill.
// Sync: R5-validated race-free ordering (__syncthreads BEFORE stage).
// Staging: 6 gll/wave (Ahi,Alo chunk w; Bh chunks w,w+8; Bl chunks w,w+8),
// granule swizzle sg=(lane&3)^((lane>>3)&3) (chunk-invariant), 0 conflicts.
#define MBT  128
#define NCH  256
#define KS   32
#define NTHR 512
#define BUFB 49152   // Ahi 8K | Alo 8K | Bh 16K | Bl 16K

__global__ __launch_bounds__(NTHR, 2)
void rvq_mfma(const float* __restrict__ xin, float* __restrict__ qout,
              const float* __restrict__ cbs,
              const f16* __restrict__ Bhi, const f16* __restrict__ Blo,
              f16* __restrict__ Ahi, f16* __restrict__ Alo,
              const float* __restrict__ c2g, float* __restrict__ idxout,
              int lvl, int is_last)
{
    __shared__ char smem[2 * BUFB];      // 98304 B -> 1 block/CU
    const int tid  = threadIdx.x;
    const int lane = tid & 63;
    const int w    = tid >> 6;           // 0..7
    const int wn   = w & 3;              // N strip (64 codebooks)
    const int wm   = w >> 2;             // M half (64 tokens)
    const int tx   = lane & 15;
    const int q    = lane >> 4;
    const size_t tok0 = (size_t)blockIdx.x * MBT;

    const f16*   Bh_l = Bhi + (size_t)lvl * KCB * DM;
    const f16*   Bl_l = Blo + (size_t)lvl * KCB * DM;
    const float* c2l  = c2g + lvl * KCB;
    const float* cbl  = cbs + (size_t)lvl * KCB * DM;

    // ---- staging (6 gll per wave, 48 x 1KB chunks per buffer) ----
    // chunk = 16 rows x 64 B (one kstep K-slice). lane l covers row l>>2,
    // granule-pos l&3; fetched data-granule sg = (l&3)^((l>>3)&3)
    // (chunk bases are multiples of 16 rows so only l contributes).
    const int rloc = lane >> 2;                      // 0..15
    const int sg   = (lane & 3) ^ ((lane >> 3) & 3);
    const int rsw  = q ^ ((tx >> 1) & 3);            // read-side granule pos

    // per-thread base pointers (hoist 64-bit math out of the loop)
    const f16* pAh = Ahi + (tok0 + w * 16 + rloc) * (size_t)DM + sg * 8;
    const f16* pAl = Alo + (tok0 + w * 16 + rloc) * (size_t)DM + sg * 8;
    const size_t bRow = (size_t)(w * 16 + rloc) * DM + sg * 8;

    auto stage = [&](char* buf, int gk2) {
        const int ko    = (gk2 & 15) * KS;                       // scalar
        const size_t bo = (size_t)((gk2 >> 4) * NCH) * DM + ko;  // scalar
        gll16(pAh + ko, buf + w * 1024);
        gll16(pAl + ko, buf + 8192 + w * 1024);
        gll16(Bh_l + bo + bRow,            buf + 16384 + w * 1024);
        gll16(Bh_l + bo + bRow + 128 * DM, buf + 16384 + (w + 8) * 1024);
        gll16(Bl_l + bo + bRow,            buf + 32768 + w * 1024);
        gll16(Bl_l + bo + bRow + 128 * DM, buf + 32768 + (w + 8) * 1024);
    };

    // ---- read-side fragment byte offsets ----
    int aoff[4], boff[4];
    #pragma unroll
    for (int i = 0; i < 4; ++i) aoff[i] = (wm * 64 + i * 16 + tx) * 64 + rsw * 16;
    #pragma unroll
    for (int j = 0; j < 4; ++j) boff[j] = (wn * 64 + j * 16 + tx) * 64 + rsw * 16;

    float bestv[16];
    int   besti[16];
    #pragma unroll
    for (int t = 0; t < 16; ++t) { bestv[t] = 3.4e38f; besti[t] = 0; }

    stage(smem, 0);   // prologue: buf0 for gk=0 (drained by first syncthreads)

    for (int ch = 0; ch < KCB / NCH; ++ch) {
        f32x4 acc[4][4];
        #pragma unroll
        for (int i = 0; i < 4; ++i)
            #pragma unroll
            for (int j = 0; j < 4; ++j) acc[i][j] = (f32x4)0.0f;

        for (int kk = 0; kk < 16; ++kk) {
            const int gk = ch * 16 + kk;             // 0..63
            char* bb = smem + (gk & 1) * BUFB;
            char* bn = smem + ((gk & 1) ^ 1) * BUFB;

            __syncthreads();                         // drains gk-1 prefetch AND
                                                     // all waves' reads of bn
            if (gk + 1 < 64)
                stage(bn, gk + 1);                   // 6 loads (k+1)

            f16x8 ah[4], al[4], bh[4], bl[4];
            #pragma unroll
            for (int i = 0; i < 4; ++i) {
                ah[i] = *(const f16x8*)(bb + aoff[i]);
                al[i] = *(const f16x8*)(bb + 8192 + aoff[i]);
            }
            #pragma unroll
            for (int j = 0; j < 4; ++j) {
                bh[j] = *(const f16x8*)(bb + 16384 + boff[j]);
                bl[j] = *(const f16x8*)(bb + 32768 + boff[j]);
            }

            __builtin_amdgcn_s_setprio(1);
            #pragma unroll
            for (int j = 0; j < 4; ++j)
                #pragma unroll
                for (int i = 0; i < 4; ++i)
                    acc[i][j] = __builtin_amdgcn_mfma_f32_16x16x32_f16(ah[i], bh[j], acc[i][j], 0, 0, 0);
            #pragma unroll
            for (int j = 0; j < 4; ++j)
                #pragma unroll
                for (int i = 0; i < 4; ++i)
                    acc[i][j] = __builtin_amdgcn_mfma_f32_16x16x32_f16(ah[i], bl[j], acc[i][j], 0, 0, 0);
            #pragma unroll
            for (int j = 0; j < 4; ++j)
                #pragma unroll
                for (int i = 0; i < 4; ++i)
                    acc[i][j] = __builtin_amdgcn_mfma_f32_16x16x32_f16(al[i], bh[j], acc[i][j], 0, 0, 0);
            __builtin_amdgcn_s_setprio(0);
        }

        // chunk argmin epilogue (C/D: col=lane&15 -> cb, row=(lane>>4)*4+reg -> token)
        const int cb0 = ch * NCH;
        #pragma unroll
        for (int j = 0; j < 4; ++j) {
            int n = cb0 + wn * 64 + j * 16 + tx;
            float c2v = c2l[n];
            #pragma unroll
            for (int i = 0; i < 4; ++i)
                #pragma unroll
                for (int r = 0; r < 4; ++r) {
                    float s = fmaf(-2.f, acc[i][j][r], c2v);
                    int t = i * 4 + r;
                    if (s < bestv[t]) { bestv[t] = s; besti[t] = n; }
                }
        }
    }

    // cross-lane argmin over tx (16 lanes; same q -> same token rows)
    #pragma unroll
    for (int t = 0; t < 16; ++t) {
        float v = bestv[t]; int bi = besti[t];
        #pragma unroll
        for (int off = 1; off < 16; off <<= 1) {
            float ov = __shfl_xor(v, off, 64);
            int   oi = __shfl_xor(bi, off, 64);
            if (ov < v || (ov == v && oi < bi)) { v = ov; bi = oi; }
        }
        bestv[t] = v; besti[t] = bi;
    }

    // cross-wave reduce over the 4 wn strips; overlay on buf0 (reads retired,
    // __syncthreads drains all outstanding ops first).
    float* redV = (float*)smem;            // [4 wn][128 m]  2 KB
    int*   redI = (int*)(smem + 2048);     // 2 KB
    int*   kbst = (int*)(smem + 4096);     // 128 ints
    __syncthreads();
    if (tx == 0) {
        #pragma unroll
        for (int i = 0; i < 4; ++i)
            #pragma unroll
            for (int r = 0; r < 4; ++r) {
                int m = wm * 64 + i * 16 + q * 4 + r;
                redV[wn * 128 + m] = bestv[i * 4 + r];
                redI[wn * 128 + m] = besti[i * 4 + r];
            }
    }
    __syncthreads();
    if (tid < MBT) {
        float bv = redV[tid]; int bi = redI[tid];
        #pragma unroll
        for (int ww = 1; ww < 4; ++ww) {
            float v  = redV[ww * 128 + tid];
            int   ii = redI[ww * 128 + tid];
            if (v < bv || (v == bv && ii < bi)) { bv = v; bi = ii; }
        }
        kbst[tid] = bi;
        idxout[(tok0 + tid) * NLV + lvl] = (float)bi;
    }
    __syncthreads();

    // residual update on biased hi/lo planes: r = hi + (lo - beta) - c
    #pragma unroll 4
    for (int it = 0; it < 16; ++it) {
        int e  = it * NTHR + tid;          // 128 tok x 64 granules of 8
        int t  = e >> 6, d8 = e & 63;
        size_t go = (tok0 + t) * (size_t)DM + d8 * 8;
        f16x8 h8 = *(const f16x8*)&Ahi[go];
        f16x8 l8 = *(const f16x8*)&Alo[go];
        const float* cp = &cbl[(size_t)kbst[t] * DM + d8 * 8];
        float4 c0 = *(const float4*)cp;
        float4 c1 = *(const float4*)(cp + 4);
        float r[8];
        r[0] = (float)h8[0] + ((float)l8[0] - BETA) - c0.x;
        r[1] = (float)h8[1] + ((float)l8[1] - BETA) - c0.y;
        r[2] = (float)h8[2] + ((float)l8[2] - BETA) - c0.z;
        r[3] = (float)h8[3] + ((float)l8[3] - BETA) - c0.w;
        r[4] = (float)h8[4] + ((float)l8[4] - BETA) - c1.x;
        r[5] = (float)h8[5] + ((float)l8[5] - BETA) - c1.y;
        r[6] = (float)h8[6] + ((float)l8[6] - BETA) - c1.z;
        r[7] = (float)h8[7] + ((float)l8[7] - BETA) - c1.w;
        if (is_last) {
            float4 x0 = *(const float4*)&xin[go];
            float4 x1 = *(const float4*)&xin[go + 4];
            float4 q0 = make_float4(x0.x - r[0], x0.y - r[1], x0.z - r[2], x0.w - r[3]);
            float4 q1 = make_float4(x1.x - r[4], x1.y - r[5], x1.z - r[6], x1.w - r[7]);
            *(float4*)&qout[go]     = q0;
            *(float4*)&qout[go + 4] = q1;
        } else {
            f16x8 h, l;
            #pragma unroll
            for (int k = 0; k < 8; ++k) {
                h[k] = (f16)r[k];
                l[k] = (f16)((r[k] - (float)h[k]) + BETA);
            }
            *(f16x8*)&Ahi[go] = h;
            *(f16x8*)&Alo[go] = l;
        }
    }
}

// =================== launch ===================
extern "C" void kernel_launch(void* const* d_in, const int* in_sizes, int n_in,
                              void* d_out, int out_size, void* d_ws, size_t ws_size,
                              hipStream_t stream) {
    const float* x   = (const float*)d_in[0];   // [8,4096,512]
    const float* cbs = (const float*)d_in[1];   // [8,1024,512]
    float* qout   = (float*)d_out;                       // [8,4096,512]
    float* idxout = qout + (size_t)NTOK * DM;            // [8,4096,8] as float

    const size_t B_ELE = (size_t)NLV * KCB * DM;   // 4,194,304
    const size_t A_ELE = (size_t)NTOK * DM;        // 16,777,216

    f16* Bhi = (f16*)d_ws;
    f16* Blo = Bhi + B_ELE;
    f16* Ahi = Blo + B_ELE;
    f16* Alo = Ahi + A_ELE;
    float* c2 = (float*)(Alo + A_ELE);

    split_kernel<<<(int)(B_ELE / 4 / 256), 256, 0, stream>>>(cbs, Bhi, Blo);
    split_kernel<<<(int)(A_ELE / 4 / 256), 256, 0, stream>>>(x, Ahi, Alo);
    c2_kernel<<<NLV * KCB, 64, 0, stream>>>(cbs, c2);

    const int nblocks = NTOK / MBT;  // 256 -> 1 block/CU
    for (int l = 0; l < NLV; ++l) {
        rvq_mfma<<<nblocks, NTHR, 0, stream>>>(x, qout, cbs,
                                               Bhi, Blo, Ahi, Alo, c2, idxout,
                                               l, (l == NLV - 1) ? 1 : 0);
    }
}

// Round 8
// 1116.918 us; speedup vs baseline: 1.2179x; 1.0172x over previous
//
#include <hip/hip_runtime.h>
#include <stdint.h>

#define NLV 8
#define KCB 1024
#define DM  512
#define NTOK (8*4096)
#define BETA 0.00390625f   // 2^-8 bias keeps lo-planes f16-normal; folds into c2'

typedef _Float16 f16;
typedef f16  f16x4 __attribute__((ext_vector_type(4)));
typedef f16  f16x8 __attribute__((ext_vector_type(8)));
typedef float f32x4 __attribute__((ext_vector_type(4)));

typedef __attribute__((address_space(1))) const unsigned int* as1p;
typedef __attribute__((address_space(3))) unsigned int*       as3p;
__device__ __forceinline__ void gll16(const void* g, void* l) {
    __builtin_amdgcn_global_load_lds((as1p)g, (as3p)l, 16, 0, 0);
}

// ---------------- c2' precompute: sum(c^2) + 2*beta*sum(f16(c)) ----------------
__global__ void c2_kernel(const float* __restrict__ cbs, float* __restrict__ c2) {
    int row  = blockIdx.x;
    int lane = threadIdx.x;
    const float4* p4 = (const float4*)(cbs + (size_t)row * DM);
    float4 a = p4[lane];
    float4 b = p4[lane + 64];
    float s = a.x*a.x + a.y*a.y + a.z*a.z + a.w*a.w
            + b.x*b.x + b.y*b.y + b.z*b.z + b.w*b.w;
    float t = (float)(f16)a.x + (float)(f16)a.y + (float)(f16)a.z + (float)(f16)a.w
            + (float)(f16)b.x + (float)(f16)b.y + (float)(f16)b.z + (float)(f16)b.w;
    #pragma unroll
    for (int off = 32; off > 0; off >>= 1) {
        s += __shfl_down(s, off, 64);
        t += __shfl_down(t, off, 64);
    }
    if (lane == 0) c2[row] = s + 2.0f * BETA * t;
}

// ---------------- hi/lo split with bias ----------------
__global__ void split_kernel(const float* __restrict__ src,
                             f16* __restrict__ hi, f16* __restrict__ lo) {
    size_t i = (size_t)blockIdx.x * 256 + threadIdx.x;   // float4 index
    float4 v = ((const float4*)src)[i];
    f16x4 h, l;
    h.x = (f16)v.x; l.x = (f16)((v.x - (float)h.x) + BETA);
    h.y = (f16)v.y; l.y = (f16)((v.y - (float)h.y) + BETA);
    h.z = (f16)v.z; l.z = (f16)((v.z - (float)h.z) + BETA);
    h.w = (f16)v.w; l.w = (f16)((v.w - (float)h.w) + BETA);
    ((f16x4*)hi)[i] = h;
    ((f16x4*)lo)[i] = l;
}

// ---------------- main MFMA level kernel ----------------
// Round 8: register-prefetch pipeline. R0/R2/R5/R6/R7 proved the ~5150-cyc
// kstep period is invariant to barrier schedule, wave count, staged volume:
// the period is the SERIAL SUM of matrix-pipe (1862/SIMD) + LDS-port (1920/CU)
// + VALU, because barrier-locked waves all read THEN all MFMA. Fix: triple-
// buffer LDS (3x48KB=144KB, 1 blk/CU, 8 waves) + register double-buffer of
// the ah/bh fragments. During kstep k: stage(k+2 -> buf[(k+2)%3]); ds_read
// k+1's ah,bh from buf[(k+1)%3] (valid: staged at k-1, drained by sync at
// top of k) into the spare reg set; MFMA(k) starts from REGISTERS (no lgkm
// wait after the barrier). al,bl read live from buf[k%3] (needed only at
// MFMA #17/#33; port delivers during pass 1). LDS port now overlaps the
// matrix pipe. Sync stays __syncthreads-before-stage (R5-validated): every
// buffer has >=1 full barrier between last read-drain and next DMA write.
//   buffers: stage at body(g) writes (g+2)%3; last reads of that buffer
//   (prefetch at body(g-2), live at body(g-... )) drained at sync(g-1) or
//   sync(g) itself -> write-after-read safe. Prefetch source (g+1)%3 valid
//   since sync(g). MFMA operands drained at sync(g).  [derivation in log]
#define MBT  128
#define NCH  256
#define KS   32
#define NTHR 512
#define BUFB 49152   // Ahi 8K | Alo 8K | Bh 16K | Bl 16K

__global__ __launch_bounds__(NTHR, 2)
void rvq_mfma(const float* __restrict__ xin, float* __restrict__ qout,
              const float* __restrict__ cbs,
              const f16* __restrict__ Bhi, const f16* __restrict__ Blo,
              f16* __restrict__ Ahi, f16* __restrict__ Alo,
              const float* __restrict__ c2g, float* __restrict__ idxout,
              int lvl, int is_last)
{
    __shared__ char smem[3 * BUFB];      // 147456 B -> 1 block/CU
    const int tid  = threadIdx.x;
    const int lane = tid & 63;
    const int w    = tid >> 6;           // 0..7
    const int wn   = w & 3;              // N strip (64 codebooks)
    const int wm   = w >> 2;             // M half (64 tokens)
    const int tx   = lane & 15;
    const int q    = lane >> 4;
    const size_t tok0 = (size_t)blockIdx.x * MBT;

    const f16*   Bh_l = Bhi + (size_t)lvl * KCB * DM;
    const f16*   Bl_l = Blo + (size_t)lvl * KCB * DM;
    const float* c2l  = c2g + lvl * KCB;
    const float* cbl  = cbs + (size_t)lvl * KCB * DM;

    // ---- staging (6 gll per wave, 48 x 1KB chunks per buffer) ----
    const int rloc = lane >> 2;                      // 0..15
    const int sg   = (lane & 3) ^ ((lane >> 3) & 3);
    const int rsw  = q ^ ((tx >> 1) & 3);            // read-side granule pos

    const f16* pAh = Ahi + (tok0 + w * 16 + rloc) * (size_t)DM + sg * 8;
    const f16* pAl = Alo + (tok0 + w * 16 + rloc) * (size_t)DM + sg * 8;
    const size_t bRow = (size_t)(w * 16 + rloc) * DM + sg * 8;

    auto stage = [&](char* buf, int gk2) {
        const int ko    = (gk2 & 15) * KS;                       // scalar
        const size_t bo = (size_t)((gk2 >> 4) * NCH) * DM + ko;  // scalar
        gll16(pAh + ko, buf + w * 1024);
        gll16(pAl + ko, buf + 8192 + w * 1024);
        gll16(Bh_l + bo + bRow,            buf + 16384 + w * 1024);
        gll16(Bh_l + bo + bRow + 128 * DM, buf + 16384 + (w + 8) * 1024);
        gll16(Bl_l + bo + bRow,            buf + 32768 + w * 1024);
        gll16(Bl_l + bo + bRow + 128 * DM, buf + 32768 + (w + 8) * 1024);
    };

    // ---- read-side fragment byte offsets ----
    int aoff[4], boff[4];
    #pragma unroll
    for (int i = 0; i < 4; ++i) aoff[i] = (wm * 64 + i * 16 + tx) * 64 + rsw * 16;
    #pragma unroll
    for (int j = 0; j < 4; ++j) boff[j] = (wn * 64 + j * 16 + tx) * 64 + rsw * 16;

    float bestv[16];
    int   besti[16];
    #pragma unroll
    for (int t = 0; t < 16; ++t) { bestv[t] = 3.4e38f; besti[t] = 0; }

    // prefetched ah/bh register double buffer (explicit E/O sets, rule #20)
    f16x8 ahE[4], bhE[4], ahO[4], bhO[4];

    // prologue: buf0<-k0; drain; buf1<-k1; prefetch k0 ah/bh -> E set
    stage(smem, 0);
    __syncthreads();
    stage(smem + BUFB, 1);
    #pragma unroll
    for (int i = 0; i < 4; ++i) ahE[i] = *(const f16x8*)(smem + aoff[i]);
    #pragma unroll
    for (int j = 0; j < 4; ++j) bhE[j] = *(const f16x8*)(smem + 16384 + boff[j]);

    // one kstep: consume C set, prefetch k+1 ah/bh into N set, al/bl live
    auto kbody = [&](int gk, f32x4 (&acc)[4][4],
                     f16x8 (&ahC)[4], f16x8 (&bhC)[4],
                     f16x8 (&ahN)[4], f16x8 (&bhN)[4]) {
        char* bufC = smem + (gk % 3) * BUFB;           // current (al/bl live)
        char* bufR = smem + ((gk + 1) % 3) * BUFB;     // prefetch source
        char* bufS = smem + ((gk + 2) % 3) * BUFB;     // stage target

        __syncthreads();   // drains: stage(k+1), prefetch reads(k), live reads(k-1)
        if (gk + 2 < 64) stage(bufS, gk + 2);

        // live reads (this kstep's al/bl): needed from MFMA #17 / #33
        f16x8 al[4], bl[4];
        #pragma unroll
        for (int i = 0; i < 4; ++i) al[i] = *(const f16x8*)(bufC + 8192 + aoff[i]);
        #pragma unroll
        for (int j = 0; j < 4; ++j) bl[j] = *(const f16x8*)(bufC + 32768 + boff[j]);

        // prefetch reads (next kstep's ah/bh): consumed after next sync
        if (gk + 1 < 64) {
            #pragma unroll
            for (int i = 0; i < 4; ++i) ahN[i] = *(const f16x8*)(bufR + aoff[i]);
            #pragma unroll
            for (int j = 0; j < 4; ++j) bhN[j] = *(const f16x8*)(bufR + 16384 + boff[j]);
        }
        __builtin_amdgcn_sched_barrier(0);   // pin reads before MFMA cluster

        __builtin_amdgcn_s_setprio(1);
        #pragma unroll
        for (int j = 0; j < 4; ++j)          // hh: pure-register, zero stall
            #pragma unroll
            for (int i = 0; i < 4; ++i)
                acc[i][j] = __builtin_amdgcn_mfma_f32_16x16x32_f16(ahC[i], bhC[j], acc[i][j], 0, 0, 0);
        #pragma unroll
        for (int j = 0; j < 4; ++j)          // hl: bl arrives during hh
            #pragma unroll
            for (int i = 0; i < 4; ++i)
                acc[i][j] = __builtin_amdgcn_mfma_f32_16x16x32_f16(ahC[i], bl[j], acc[i][j], 0, 0, 0);
        #pragma unroll
        for (int j = 0; j < 4; ++j)          // lh: al arrives during hh/hl
            #pragma unroll
            for (int i = 0; i < 4; ++i)
                acc[i][j] = __builtin_amdgcn_mfma_f32_16x16x32_f16(al[i], bhC[j], acc[i][j], 0, 0, 0);
        __builtin_amdgcn_s_setprio(0);
    };

    for (int ch = 0; ch < KCB / NCH; ++ch) {
        f32x4 acc[4][4];
        #pragma unroll
        for (int i = 0; i < 4; ++i)
            #pragma unroll
            for (int j = 0; j < 4; ++j) acc[i][j] = (f32x4)0.0f;

        for (int kp = 0; kp < 8; ++kp) {     // 16 ksteps as E/O pairs
            const int gk = ch * 16 + kp * 2;
            kbody(gk,     acc, ahE, bhE, ahO, bhO);
            kbody(gk + 1, acc, ahO, bhO, ahE, bhE);
        }

        // chunk argmin epilogue (C/D: col=lane&15 -> cb, row=(lane>>4)*4+reg -> token)
        const int cb0 = ch * NCH;
        #pragma unroll
        for (int j = 0; j < 4; ++j) {
            int n = cb0 + wn * 64 + j * 16 + tx;
            float c2v = c2l[n];
            #pragma unroll
            for (int i = 0; i < 4; ++i)
                #pragma unroll
                for (int r = 0; r < 4; ++r) {
                    float s = fmaf(-2.f, acc[i][j][r], c2v);
                    int t = i * 4 + r;
                    if (s < bestv[t]) { bestv[t] = s; besti[t] = n; }
                }
        }
    }

    // cross-lane argmin over tx (16 lanes; same q -> same token rows)
    #pragma unroll
    for (int t = 0; t < 16; ++t) {
        float v = bestv[t]; int bi = besti[t];
        #pragma unroll
        for (int off = 1; off < 16; off <<= 1) {
            float ov = __shfl_xor(v, off, 64);
            int   oi = __shfl_xor(bi, off, 64);
            if (ov < v || (ov == v && oi < bi)) { v = ov; bi = oi; }
        }
        bestv[t] = v; besti[t] = bi;
    }

    // cross-wave reduce over the 4 wn strips; overlay on buf0 (the final
    // __syncthreads drains the last live reads of buf0 at gk=63).
    float* redV = (float*)smem;            // [4 wn][128 m]  2 KB
    int*   redI = (int*)(smem + 2048);     // 2 KB
    int*   kbst = (int*)(smem + 4096);     // 128 ints
    __syncthreads();
    if (tx == 0) {
        #pragma unroll
        for (int i = 0; i < 4; ++i)
            #pragma unroll
            for (int r = 0; r < 4; ++r) {
                int m = wm * 64 + i * 16 + q * 4 + r;
                redV[wn * 128 + m] = bestv[i * 4 + r];
                redI[wn * 128 + m] = besti[i * 4 + r];
            }
    }
    __syncthreads();
    if (tid < MBT) {
        float bv = redV[tid]; int bi = redI[tid];
        #pragma unroll
        for (int ww = 1; ww < 4; ++ww) {
            float v  = redV[ww * 128 + tid];
            int   ii = redI[ww * 128 + tid];
            if (v < bv || (v == bv && ii < bi)) { bv = v; bi = ii; }
        }
        kbst[tid] = bi;
        idxout[(tok0 + tid) * NLV + lvl] = (float)bi;
    }
    __syncthreads();

    // residual update on biased hi/lo planes: r = hi + (lo - beta) - c
    #pragma unroll 4
    for (int it = 0; it < 16; ++it) {
        int e  = it * NTHR + tid;          // 128 tok x 64 granules of 8
        int t  = e >> 6, d8 = e & 63;
        size_t go = (tok0 + t) * (size_t)DM + d8 * 8;
        f16x8 h8 = *(const f16x8*)&Ahi[go];
        f16x8 l8 = *(const f16x8*)&Alo[go];
        const float* cp = &cbl[(size_t)kbst[t] * DM + d8 * 8];
        float4 c0 = *(const float4*)cp;
        float4 c1 = *(const float4*)(cp + 4);
        float r[8];
        r[0] = (float)h8[0] + ((float)l8[0] - BETA) - c0.x;
        r[1] = (float)h8[1] + ((float)l8[1] - BETA) - c0.y;
        r[2] = (float)h8[2] + ((float)l8[2] - BETA) - c0.z;
        r[3] = (float)h8[3] + ((float)l8[3] - BETA) - c0.w;
        r[4] = (float)h8[4] + ((float)l8[4] - BETA) - c1.x;
        r[5] = (float)h8[5] + ((float)l8[5] - BETA) - c1.y;
        r[6] = (float)h8[6] + ((float)l8[6] - BETA) - c1.z;
        r[7] = (float)h8[7] + ((float)l8[7] - BETA) - c1.w;
        if (is_last) {
            float4 x0 = *(const float4*)&xin[go];
            float4 x1 = *(const float4*)&xin[go + 4];
            float4 q0 = make_float4(x0.x - r[0], x0.y - r[1], x0.z - r[2], x0.w - r[3]);
            float4 q1 = make_float4(x1.x - r[4], x1.y - r[5], x1.z - r[6], x1.w - r[7]);
            *(float4*)&qout[go]     = q0;
            *(float4*)&qout[go + 4] = q1;
        } else {
            f16x8 h, l;
            #pragma unroll
            for (int k = 0; k < 8; ++k) {
                h[k] = (f16)r[k];
                l[k] = (f16)((r[k] - (float)h[k]) + BETA);
            }
            *(f16x8*)&Ahi[go] = h;
            *(f16x8*)&Alo[go] = l;
        }
    }
}

// =================== launch ===================
extern "C" void kernel_launch(void* const* d_in, const int* in_sizes, int n_in,
                              void* d_out, int out_size, void* d_ws, size_t ws_size,
                              hipStream_t stream) {
    const float* x   = (const float*)d_in[0];   // [8,4096,512]
    const float* cbs = (const float*)d_in[1];   // [8,1024,512]
    float* qout   = (float*)d_out;                       // [8,4096,512]
    float* idxout = qout + (size_t)NTOK * DM;            // [8,4096,8] as float

    const size_t B_ELE = (size_t)NLV * KCB * DM;   // 4,194,304
    const size_t A_ELE = (size_t)NTOK * DM;        // 16,777,216

    f16* Bhi = (f16*)d_ws;
    f16* Blo = Bhi + B_ELE;
    f16* Ahi = Blo + B_ELE;
    f16* Alo = Ahi + A_ELE;
    float* c2 = (float*)(Alo + A_ELE);

    split_kernel<<<(int)(B_ELE / 4 / 256), 256, 0, stream>>>(cbs, Bhi, Blo);
    split_kernel<<<(int)(A_ELE / 4 / 256), 256, 0, stream>>>(x, Ahi, Alo);
    c2_kernel<<<NLV * KCB, 64, 0, stream>>>(cbs, c2);

    const int nblocks = NTOK / MBT;  // 256 -> 1 block/CU
    for (int l = 0; l < NLV; ++l) {
        rvq_mfma<<<nblocks, NTHR, 0, stream>>>(x, qout, cbs,
                                               Bhi, Blo, Ahi, Alo, c2, idxout,
                                               l, (l == NLV - 1) ? 1 : 0);
    }
}